// Round 3
// baseline (4765.682 us; speedup 1.0000x reference)
//
#include <hip/hip_runtime.h>
#include <hip/hip_cooperative_groups.h>
#include <stdint.h>

namespace cg = cooperative_groups;

#define B_ 64
#define D_ 1024
#define H_ 1024
#define V_ 32000
#define T_ 20

typedef __attribute__((ext_vector_type(8))) __bf16 bf16x8;
typedef __attribute__((ext_vector_type(4))) float f32x4;

#define LSTRIDE 72  // 64 + 8 pad

// ---------------------------------------------------------------- helpers
__device__ __forceinline__ uint32_t ord_of_float(float x) {
    uint32_t u = __float_as_uint(x);
    return (u & 0x80000000u) ? ~u : (u | 0x80000000u);
}

__device__ __forceinline__ unsigned long long shfl_xor_u64(unsigned long long x, int m) {
    return (unsigned long long)__shfl_xor((long long)x, m, 64);
}

__device__ __forceinline__ void split_bf16(float f, unsigned short* hi, unsigned short* lo) {
    uint32_t u = __float_as_uint(f);
    uint32_t rh = (u + 0x7FFFu + ((u >> 16) & 1u)) >> 16;
    *hi = (unsigned short)rh;
    float fl = f - __uint_as_float(rh << 16);
    uint32_t ul = __float_as_uint(fl);
    uint32_t rl = (ul + 0x7FFFu + ((ul >> 16) & 1u)) >> 16;
    *lo = (unsigned short)rl;
}

// One K=64 chunk of a 64x64 split-bf16 MFMA tile: load 16 fp32 A + 16 fp32 B
// per thread, split to hi/lo bf16 in LDS, run 24 MFMAs (3-term product).
__device__ __forceinline__ void gemm_kc(
    const float* __restrict__ asrc, const float* __restrict__ bsrc,
    unsigned short* Ahi, unsigned short* Alo,
    unsigned short* Bhi, unsigned short* Blo,
    int srow, int scol, int arow_f, int koff, int lane, f32x4* acc)
{
    float4 av[4], bv[4];
#pragma unroll
    for (int i = 0; i < 4; i++) {
        av[i] = *(const float4*)(asrc + 4 * i);
        bv[i] = *(const float4*)(bsrc + 4 * i);
    }
    __syncthreads();
    unsigned short* ahd = Ahi + srow * LSTRIDE + scol;
    unsigned short* ald = Alo + srow * LSTRIDE + scol;
    unsigned short* bhd = Bhi + srow * LSTRIDE + scol;
    unsigned short* bld = Blo + srow * LSTRIDE + scol;
#pragma unroll
    for (int i = 0; i < 4; i++) {
        split_bf16(av[i].x, ahd + 4 * i + 0, ald + 4 * i + 0);
        split_bf16(av[i].y, ahd + 4 * i + 1, ald + 4 * i + 1);
        split_bf16(av[i].z, ahd + 4 * i + 2, ald + 4 * i + 2);
        split_bf16(av[i].w, ahd + 4 * i + 3, ald + 4 * i + 3);
        split_bf16(bv[i].x, bhd + 4 * i + 0, bld + 4 * i + 0);
        split_bf16(bv[i].y, bhd + 4 * i + 1, bld + 4 * i + 1);
        split_bf16(bv[i].z, bhd + 4 * i + 2, bld + 4 * i + 2);
        split_bf16(bv[i].w, bhd + 4 * i + 3, bld + 4 * i + 3);
    }
    __syncthreads();
    bf16x8 ah0 = *(const bf16x8*)(Ahi + arow_f * LSTRIDE + koff);
    bf16x8 ah1 = *(const bf16x8*)(Ahi + arow_f * LSTRIDE + 32 + koff);
    bf16x8 al0 = *(const bf16x8*)(Alo + arow_f * LSTRIDE + koff);
    bf16x8 al1 = *(const bf16x8*)(Alo + arow_f * LSTRIDE + 32 + koff);
#pragma unroll
    for (int tv = 0; tv < 4; tv++) {
        int brow = tv * 16 + (lane & 15);
        bf16x8 bh0 = *(const bf16x8*)(Bhi + brow * LSTRIDE + koff);
        bf16x8 bh1 = *(const bf16x8*)(Bhi + brow * LSTRIDE + 32 + koff);
        bf16x8 bl0 = *(const bf16x8*)(Blo + brow * LSTRIDE + koff);
        bf16x8 bl1 = *(const bf16x8*)(Blo + brow * LSTRIDE + 32 + koff);
        acc[tv] = __builtin_amdgcn_mfma_f32_16x16x32_bf16(ah0, bh0, acc[tv], 0, 0, 0);
        acc[tv] = __builtin_amdgcn_mfma_f32_16x16x32_bf16(ah1, bh1, acc[tv], 0, 0, 0);
        acc[tv] = __builtin_amdgcn_mfma_f32_16x16x32_bf16(al0, bh0, acc[tv], 0, 0, 0);
        acc[tv] = __builtin_amdgcn_mfma_f32_16x16x32_bf16(al1, bh1, acc[tv], 0, 0, 0);
        acc[tv] = __builtin_amdgcn_mfma_f32_16x16x32_bf16(ah0, bl0, acc[tv], 0, 0, 0);
        acc[tv] = __builtin_amdgcn_mfma_f32_16x16x32_bf16(ah1, bl1, acc[tv], 0, 0, 0);
    }
}

// ================================================================ persistent
// Grid 512 x 256, cooperative.  LDS ~37.6 KB -> 2 blocks/CU.
__global__ __launch_bounds__(256, 2) void k_persist(
    const float* __restrict__ latent, const float* __restrict__ Wp,
    const float* __restrict__ bp, const float* __restrict__ emb,
    const float* __restrict__ Wih, const float* __restrict__ bih,
    const float* __restrict__ Whh, const float* __restrict__ bhh,
    const float* __restrict__ Wout, const float* __restrict__ bout,
    float* __restrict__ out, char* __restrict__ ws)
{
    cg::grid_group grid = cg::this_grid();

    __shared__ unsigned short Ahi[64 * LSTRIDE], Alo[64 * LSTRIDE];
    __shared__ unsigned short Bhi[64 * LSTRIDE], Blo[64 * LSTRIDE];
    __shared__ int tokLds[64];
    __shared__ unsigned long long redLds[64];

    float* hb0 = (float*)ws;                                     // 256 KB
    float* hb1 = (float*)(ws + 262144);                          // 256 KB
    unsigned long long* partials = (unsigned long long*)(ws + 524288); // 500*64*8
    float* gbuf = (float*)(ws + 786432);                         // 6 MB

    int tid = threadIdx.x;
    int lane = tid & 63;
    int wv = tid >> 6;
    int bx = blockIdx.x;
    int srow = tid >> 2;
    int scol = (tid & 3) * 16;
    int arow_f = wv * 16 + (lane & 15);
    int koff = (lane >> 4) * 8;
    int col = lane & 15;
    int quad = lane >> 4;

    // ---------------- phase: init hidden  h0 = latent @ Wp^T + bp
    if (bx < 16) {
        int jt = bx;
        const float* asrc = latent + srow * D_ + scol;
        const float* bsrc = Wp + (size_t)(jt * 64 + srow) * D_ + scol;
        f32x4 acc[4];
#pragma unroll
        for (int i = 0; i < 4; i++) acc[i] = (f32x4){0.f, 0.f, 0.f, 0.f};
        for (int kc = 0; kc < D_; kc += 64)
            gemm_kc(asrc + kc, bsrc + kc, Ahi, Alo, Bhi, Blo,
                    srow, scol, arow_f, koff, lane, acc);
#pragma unroll
        for (int tv = 0; tv < 4; tv++) {
            int j = jt * 64 + tv * 16 + col;
#pragma unroll
            for (int r = 0; r < 4; r++) {
                int b = wv * 16 + quad * 4 + r;
                hb0[b * H_ + j] = acc[tv][r] + bp[j];
            }
        }
    }
    grid.sync();

    for (int t = 0; t < T_; t++) {
        const float* hprev = (t & 1) ? hb1 : hb0;
        float* hnext = (t & 1) ? hb0 : hb1;

        // ---------------- phase: gates GEMM (384 tiles: 48 jt x 2 half x 4 ks)
        if (bx < 384) {
            int jt = bx % 48;
            int rest = bx / 48;
            int half = rest & 1;
            int ks = rest >> 1;
            int kbase = ks * 256;

            if (half == 0) {
                // derive token for all 64 b from previous step's partials
                if (t == 0) {
                    if (tid < 64) tokLds[tid] = 0;  // SOS
                } else {
                    int b = tid & 63, chunk = tid >> 6;
                    unsigned long long k = 0ull;
                    int i0 = chunk * 125;
                    for (int i = i0; i < i0 + 125; i++) {
                        unsigned long long p = partials[(size_t)i * 64 + b];
                        if (p > k) k = p;
                    }
                    if (tid < 64) redLds[tid] = 0ull;
                    __syncthreads();
                    atomicMax(&redLds[b], k);
                    __syncthreads();
                    if (tid < 64)
                        tokLds[tid] = (int)(0x7FFFFFFFu -
                                      (uint32_t)(redLds[tid] & 0xFFFFFFFFull));
                }
            }
            __syncthreads();
            if (bx == 0 && t > 0 && tid < 64)
                out[tid * T_ + (t - 1)] = (float)tokLds[tid];

            const float* asrc;
            if (half == 0)
                asrc = emb + (size_t)tokLds[srow] * H_ + kbase + scol;
            else
                asrc = hprev + srow * H_ + kbase + scol;
            const float* W = half ? Whh : Wih;
            const float* bsrc = W + (size_t)(jt * 64 + srow) * H_ + kbase + scol;

            f32x4 acc[4];
#pragma unroll
            for (int i = 0; i < 4; i++) acc[i] = (f32x4){0.f, 0.f, 0.f, 0.f};
            for (int kc = 0; kc < 256; kc += 64)
                gemm_kc(asrc + kc, bsrc + kc, Ahi, Alo, Bhi, Blo,
                        srow, scol, arow_f, koff, lane, acc);

            float* og = gbuf + (size_t)((ks * 2 + half) * 64) * 3072;
#pragma unroll
            for (int tv = 0; tv < 4; tv++) {
#pragma unroll
                for (int r = 0; r < 4; r++) {
                    int b = wv * 16 + quad * 4 + r;
                    og[(size_t)b * 3072 + jt * 64 + tv * 16 + col] = acc[tv][r];
                }
            }
        }
        grid.sync();

        // ---------------- phase: elementwise GRU
        {
            int gid = bx * 256 + tid;
            if (gid < 65536) {
                int b = gid >> 10, j = gid & 1023;
                float ir = bih[j], iz = bih[H_ + j], in_ = bih[2 * H_ + j];
                float hr = bhh[j], hz = bhh[H_ + j], hn = bhh[2 * H_ + j];
#pragma unroll
                for (int ks = 0; ks < 4; ks++) {
                    const float* gi = gbuf + (size_t)((ks * 2 + 0) * 64 + b) * 3072;
                    const float* gh = gbuf + (size_t)((ks * 2 + 1) * 64 + b) * 3072;
                    ir += gi[j];          hr += gh[j];
                    iz += gi[H_ + j];     hz += gh[H_ + j];
                    in_ += gi[2 * H_ + j]; hn += gh[2 * H_ + j];
                }
                float r = 1.f / (1.f + expf(-(ir + hr)));
                float z = 1.f / (1.f + expf(-(iz + hz)));
                float n = tanhf(in_ + r * hn);
                hnext[gid] = (1.f - z) * n + z * hprev[gid];
            }
        }
        grid.sync();

        // ---------------- phase: logits + block argmax (500 tiles)
        if (bx < 500) {
            const float* asrc = hnext + srow * H_ + scol;
            const float* bsrc = Wout + (size_t)(bx * 64 + srow) * H_ + scol;
            f32x4 acc[4];
#pragma unroll
            for (int i = 0; i < 4; i++) acc[i] = (f32x4){0.f, 0.f, 0.f, 0.f};
            for (int kc = 0; kc < H_; kc += 64)
                gemm_kc(asrc + kc, bsrc + kc, Ahi, Alo, Bhi, Blo,
                        srow, scol, arow_f, koff, lane, acc);

            unsigned long long kmax[4] = {0ull, 0ull, 0ull, 0ull};
#pragma unroll
            for (int tv = 0; tv < 4; tv++) {
                int v = bx * 64 + tv * 16 + col;
                float bo = bout[v];
#pragma unroll
                for (int r = 0; r < 4; r++) {
                    float lg = acc[tv][r] + bo;
                    unsigned long long key =
                        ((unsigned long long)ord_of_float(lg) << 32)
                        | (unsigned long long)(0x7FFFFFFFu - (uint32_t)v);
                    if (key > kmax[r]) kmax[r] = key;
                }
            }
#pragma unroll
            for (int r = 0; r < 4; r++) {
                unsigned long long k = kmax[r];
#pragma unroll
                for (int off = 1; off < 16; off <<= 1) {
                    unsigned long long o = shfl_xor_u64(k, off);
                    if (o > k) k = o;
                }
                kmax[r] = k;
            }
            if (col == 0) {
#pragma unroll
                for (int r = 0; r < 4; r++) {
                    int b = wv * 16 + quad * 4 + r;
                    partials[(size_t)bx * 64 + b] = kmax[r];
                }
            }
        }
        grid.sync();
    }

    // ---------------- final: token t=19 + h_final copy
    if (bx < 64) {
        int b = bx;
        unsigned long long k = 0ull;
        for (int i = tid; i < 500; i += 256) {
            unsigned long long p = partials[(size_t)i * 64 + b];
            if (p > k) k = p;
        }
#pragma unroll
        for (int off = 32; off; off >>= 1) {
            unsigned long long o = shfl_xor_u64(k, off);
            if (o > k) k = o;
        }
        if (lane == 0) redLds[wv] = k;
        __syncthreads();
        if (tid == 0) {
            unsigned long long km = redLds[0];
            for (int i = 1; i < 4; i++) if (redLds[i] > km) km = redLds[i];
            out[b * T_ + 19] =
                (float)(int)(0x7FFFFFFFu - (uint32_t)(km & 0xFFFFFFFFull));
        }
    }
    {
        int gid = bx * 256 + tid;
        if (gid < 16384) {
            ((float4*)(out + B_ * T_))[gid] = ((const float4*)hb0)[gid];
        }
    }
}

// ================================================================ fallback
// (R2 multi-kernel path, used only if cooperative launch is rejected)
__global__ __launch_bounds__(256) void k_init_hidden(
    const float* __restrict__ latent, const float* __restrict__ Wp,
    const float* __restrict__ bp, float* __restrict__ h0)
{
    int gw = (blockIdx.x * 256 + threadIdx.x) >> 6;
    int lane = threadIdx.x & 63;
    int j = gw >> 6;
    int b = gw & 63;
    const float4* a4 = (const float4*)(latent + b * D_);
    const float4* w4 = (const float4*)(Wp + (size_t)j * D_);
    float s = 0.f;
#pragma unroll
    for (int i = 0; i < 4; i++) {
        float4 a = a4[lane + 64 * i];
        float4 w = w4[lane + 64 * i];
        s += a.x * w.x + a.y * w.y + a.z * w.z + a.w * w.w;
    }
#pragma unroll
    for (int off = 32; off; off >>= 1) s += __shfl_down(s, off, 64);
    if (lane == 0) h0[b * H_ + j] = s + bp[j];
}

__global__ __launch_bounds__(256) void k_gates_gemm(
    const float* __restrict__ emb, const int* __restrict__ tok, int use_sos,
    const float* __restrict__ hprev, const float* __restrict__ Wih,
    const float* __restrict__ Whh, float* __restrict__ gbuf)
{
    __shared__ unsigned short Ahi[64 * LSTRIDE], Alo[64 * LSTRIDE];
    __shared__ unsigned short Bhi[64 * LSTRIDE], Blo[64 * LSTRIDE];
    int tid = threadIdx.x;
    int lane = tid & 63;
    int wv = tid >> 6;
    int blk = blockIdx.x;
    int jt = blk % 48;
    int rest = blk / 48;
    int half = rest & 1;
    int ks = rest >> 1;
    int kbase = ks * 512;
    const float* W = half ? Whh : Wih;
    int srow = tid >> 2;
    int scol = (tid & 3) * 16;
    const float* arow;
    if (half == 0) {
        int xr = use_sos ? 0 : tok[srow];
        arow = emb + (size_t)xr * H_;
    } else {
        arow = hprev + srow * H_;
    }
    const float* asrc = arow + kbase + scol;
    const float* bsrc = W + (size_t)(jt * 64 + srow) * H_ + kbase + scol;
    f32x4 acc[4];
#pragma unroll
    for (int i = 0; i < 4; i++) acc[i] = (f32x4){0.f, 0.f, 0.f, 0.f};
    int arow_f = wv * 16 + (lane & 15);
    int koff = (lane >> 4) * 8;
    for (int kc = 0; kc < 512; kc += 64)
        gemm_kc(asrc + kc, bsrc + kc, Ahi, Alo, Bhi, Blo,
                srow, scol, arow_f, koff, lane, acc);
    int col = lane & 15;
    int quad = lane >> 4;
    float* og = gbuf + (size_t)((ks * 2 + half) * 64) * 3072;
#pragma unroll
    for (int tv = 0; tv < 4; tv++)
#pragma unroll
        for (int r = 0; r < 4; r++) {
            int b = wv * 16 + quad * 4 + r;
            og[(size_t)b * 3072 + jt * 64 + tv * 16 + col] = acc[tv][r];
        }
}

__global__ __launch_bounds__(256) void k_gru_elem(
    const float* __restrict__ gbuf, const float* __restrict__ bih,
    const float* __restrict__ bhh, const float* __restrict__ hprev,
    float* __restrict__ hnext)
{
    int idx = blockIdx.x * 256 + threadIdx.x;
    int b = idx >> 10;
    int j = idx & 1023;
    const float* g00 = gbuf + (size_t)b * 3072;
    const float* g01 = gbuf + (size_t)(64 + b) * 3072;
    const float* g10 = gbuf + (size_t)(128 + b) * 3072;
    const float* g11 = gbuf + (size_t)(192 + b) * 3072;
    float ir = g00[j] + g10[j] + bih[j];
    float hr = g01[j] + g11[j] + bhh[j];
    float iz = g00[H_ + j] + g10[H_ + j] + bih[H_ + j];
    float hz = g01[H_ + j] + g11[H_ + j] + bhh[H_ + j];
    float in_ = g00[2 * H_ + j] + g10[2 * H_ + j] + bih[2 * H_ + j];
    float hn = g01[2 * H_ + j] + g11[2 * H_ + j] + bhh[2 * H_ + j];
    float r = 1.f / (1.f + expf(-(ir + hr)));
    float z = 1.f / (1.f + expf(-(iz + hz)));
    float n = tanhf(in_ + r * hn);
    hnext[idx] = (1.f - z) * n + z * hprev[idx];
}

__global__ __launch_bounds__(256) void k_logits_argmax(
    const float* __restrict__ hcur, const float* __restrict__ Wout,
    const float* __restrict__ bout, unsigned long long* __restrict__ partials,
    int nblk)
{
    __shared__ unsigned short Ahi[64 * LSTRIDE], Alo[64 * LSTRIDE];
    __shared__ unsigned short Bhi[64 * LSTRIDE], Blo[64 * LSTRIDE];
    int tid = threadIdx.x;
    int lane = tid & 63;
    int wv = tid >> 6;
    int vbase = blockIdx.x * 64;
    int srow = tid >> 2;
    int scol = (tid & 3) * 16;
    const float* asrc = hcur + srow * H_ + scol;
    const float* bsrc = Wout + (size_t)(vbase + srow) * H_ + scol;
    f32x4 acc[4];
#pragma unroll
    for (int i = 0; i < 4; i++) acc[i] = (f32x4){0.f, 0.f, 0.f, 0.f};
    int arow_f = wv * 16 + (lane & 15);
    int koff = (lane >> 4) * 8;
    for (int kc = 0; kc < H_; kc += 64)
        gemm_kc(asrc + kc, bsrc + kc, Ahi, Alo, Bhi, Blo,
                srow, scol, arow_f, koff, lane, acc);
    int col = lane & 15;
    int quad = lane >> 4;
    unsigned long long kmax[4] = {0ull, 0ull, 0ull, 0ull};
#pragma unroll
    for (int tv = 0; tv < 4; tv++) {
        int v = vbase + tv * 16 + col;
        float bo = bout[v];
#pragma unroll
        for (int r = 0; r < 4; r++) {
            float lg = acc[tv][r] + bo;
            unsigned long long key = ((unsigned long long)ord_of_float(lg) << 32)
                                   | (unsigned long long)(0x7FFFFFFFu - (uint32_t)v);
            if (key > kmax[r]) kmax[r] = key;
        }
    }
#pragma unroll
    for (int r = 0; r < 4; r++) {
        unsigned long long k = kmax[r];
#pragma unroll
        for (int off = 1; off < 16; off <<= 1) {
            unsigned long long o = shfl_xor_u64(k, off);
            if (o > k) k = o;
        }
        kmax[r] = k;
    }
    if (col == 0)
#pragma unroll
        for (int r = 0; r < 4; r++) {
            int b = wv * 16 + quad * 4 + r;
            partials[(size_t)b * nblk + blockIdx.x] = kmax[r];
        }
}

__global__ __launch_bounds__(64) void k_token(
    const unsigned long long* __restrict__ partials, int nblk,
    int* __restrict__ tok, float* __restrict__ out_tokens, int t)
{
    int b = blockIdx.x;
    int lane = threadIdx.x;
    unsigned long long k = 0ull;
    for (int i = lane; i < nblk; i += 64) {
        unsigned long long p = partials[(size_t)b * nblk + i];
        if (p > k) k = p;
    }
#pragma unroll
    for (int off = 32; off; off >>= 1) {
        unsigned long long o = shfl_xor_u64(k, off);
        if (o > k) k = o;
    }
    if (lane == 0) {
        int v = (int)(0x7FFFFFFFu - (uint32_t)(k & 0xFFFFFFFFull));
        tok[b] = v;
        out_tokens[b * T_ + t] = (float)v;
    }
}

__global__ __launch_bounds__(256) void k_copy_h(const float* __restrict__ h,
                                               float* __restrict__ out)
{
    int i = (blockIdx.x * 256 + threadIdx.x) * 4;
    *(float4*)(out + i) = *(const float4*)(h + i);
}

// ================================================================ launch
extern "C" void kernel_launch(void* const* d_in, const int* in_sizes, int n_in,
                              void* d_out, int out_size, void* d_ws, size_t ws_size,
                              hipStream_t stream)
{
    const float* latent = (const float*)d_in[0];
    const float* Wp     = (const float*)d_in[1];
    const float* bp     = (const float*)d_in[2];
    const float* emb    = (const float*)d_in[3];
    const float* Wih    = (const float*)d_in[4];
    const float* bih    = (const float*)d_in[5];
    const float* Whh    = (const float*)d_in[6];
    const float* bhh    = (const float*)d_in[7];
    const float* Wout   = (const float*)d_in[8];
    const float* bout   = (const float*)d_in[9];
    float* out = (float*)d_out;
    char* ws = (char*)d_ws;

    void* args[] = {
        (void*)&latent, (void*)&Wp, (void*)&bp, (void*)&emb,
        (void*)&Wih, (void*)&bih, (void*)&Whh, (void*)&bhh,
        (void*)&Wout, (void*)&bout, (void*)&out, (void*)&ws
    };
    hipError_t e = hipLaunchCooperativeKernel((const void*)k_persist,
                                              dim3(512), dim3(256),
                                              args, 0, stream);
    if (e == hipSuccess) return;

    // -------- fallback: R2 multi-kernel path
    float* h0 = (float*)ws;
    float* h1 = (float*)(ws + 262144);
    int* tok  = (int*)(ws + 524288);
    unsigned long long* partials = (unsigned long long*)(ws + 525312);
    float* gbuf = (float*)(ws + 8388608);
    const int NBLK = V_ / 64;

    k_init_hidden<<<16384, 256, 0, stream>>>(latent, Wp, bp, h0);
    float* hp = h0;
    float* hn = h1;
    for (int t = 0; t < T_; t++) {
        k_gates_gemm<<<192, 256, 0, stream>>>(emb, tok, t == 0 ? 1 : 0,
                                              hp, Wih, Whh, gbuf);
        k_gru_elem<<<256, 256, 0, stream>>>(gbuf, bih, bhh, hp, hn);
        k_logits_argmax<<<NBLK, 256, 0, stream>>>(hn, Wout, bout, partials, NBLK);
        k_token<<<B_, 64, 0, stream>>>(partials, NBLK, tok, out, t);
        float* tmp = hp; hp = hn; hn = tmp;
    }
    k_copy_h<<<64, 256, 0, stream>>>(hp, out + B_ * T_);
}